// Round 14
// baseline (1396.966 us; speedup 1.0000x reference)
//
#include <hip/hip_runtime.h>
#include <math.h>

#define F 128
#define ZD 272
#define EDIM 16
#define EPS 1e-5f
#define CHK 64           // edges per chunk (one wave-pair)

typedef unsigned int u32;
typedef float v2f __attribute__((ext_vector_type(2)));

__device__ __forceinline__ u32 f2bf(float a) {
  u32 u = __float_as_uint(a);
  u += 0x7FFF + ((u >> 16) & 1);   // RNE
  return u >> 16;
}

// ---------------------------------------------------------------------------
// Fused kernel: node-table GEMM (even blocks) || CSR fill (odd blocks).
//   tabdst[n][f] = float2 {dst-filter(+bf), dst-softplus(+bs)} interleaved f32
//   tabsrc[n][f] = u32 {bf16 srcF | bf16 srcS<<16}, halves written directly
// ---------------------------------------------------------------------------
__global__ __launch_bounds__(256) void gemm_fill(
    const float* __restrict__ x, const float* __restrict__ Wf,
    const float* __restrict__ Ws, const float* __restrict__ bf,
    const float* __restrict__ bs, float* __restrict__ tabdst,
    unsigned short* __restrict__ tabsrc16, int N,
    const int* __restrict__ dst, const int* __restrict__ srcA,
    const float* __restrict__ ea, int* __restrict__ cursor,
    int2* __restrict__ sd, float* __restrict__ eap, int E,
    int gB, int fB)
{
  __shared__ float As[64][76];  // [k][m]   (gemm role only)
  __shared__ float Bs[64][76];  // [k][n]
  const int b = blockIdx.x;
  const int tid = threadIdx.x;

  if ((b & 1) == 1) {
    // ---------------- fill role (odd blocks) ----------------
    const int b2 = b >> 1;
    if (b2 >= fB) return;
    int e = b2 * 256 + tid;
    if (e < E) {
      int d = dst[e];
      int pos = atomicAdd(&cursor[d], 1);
      sd[pos] = make_int2(srcA[e], d);
      const float4* s4 = (const float4*)(ea + (size_t)e * EDIM);
      float4 a = s4[0], bb = s4[1], c = s4[2], dd = s4[3];
      float4* d4 = (float4*)(eap + (size_t)pos * EDIM);
      d4[0] = a; d4[1] = bb; d4[2] = c; d4[3] = dd;
    }
    return;
  }

  // ---------------- gemm role (even blocks) ----------------
  const int b2 = b >> 1;
  if (b2 >= gB) return;
  const int bm = b2 >> 3, bn = b2 & 7;
  const int t = bn >> 1;                 // 0..3
  const int fbase = (bn & 1) * 64;       // 0 or 64
  const float* W = (t & 1) ? Ws : Wf;
  const int koff = (t >= 2) ? F : 0;
  const int kq = (tid & 15) * 4;
  const int rr = tid >> 4;

  const int tx = tid & 15, ty = tid >> 4;
  const int m0 = ty * 4, n0 = tx * 4;
  float acc[4][4] = {};

  for (int kk = 0; kk < F; kk += 64) {
    #pragma unroll
    for (int it = 0; it < 4; ++it) {
      int row = it * 16 + rr;
      int node = bm * 64 + row;
      float4 v = make_float4(0.f, 0.f, 0.f, 0.f);
      if (node < N) v = *(const float4*)(x + (size_t)node * F + kk + kq);
      As[kq + 0][row] = v.x; As[kq + 1][row] = v.y;
      As[kq + 2][row] = v.z; As[kq + 3][row] = v.w;
    }
    #pragma unroll
    for (int it = 0; it < 4; ++it) {
      int n = it * 16 + rr;
      float4 v = *(const float4*)(W + (size_t)(fbase + n) * ZD + koff + kk + kq);
      Bs[kq + 0][n] = v.x; Bs[kq + 1][n] = v.y;
      Bs[kq + 2][n] = v.z; Bs[kq + 3][n] = v.w;
    }
    __syncthreads();
    #pragma unroll 8
    for (int k = 0; k < 64; ++k) {
      float4 a = *(const float4*)&As[k][m0];
      float4 bb = *(const float4*)&Bs[k][n0];
      float av[4] = {a.x, a.y, a.z, a.w};
      float bv[4] = {bb.x, bb.y, bb.z, bb.w};
      #pragma unroll
      for (int i = 0; i < 4; ++i)
        #pragma unroll
        for (int j = 0; j < 4; ++j)
          acc[i][j] += av[i] * bv[j];
    }
    __syncthreads();
  }

  #pragma unroll
  for (int i = 0; i < 4; ++i) {
    int node = bm * 64 + m0 + i;
    if (node >= N) continue;
    #pragma unroll
    for (int j = 0; j < 4; ++j) {
      int fcol = fbase + n0 + j;
      float v = acc[i][j];
      size_t idx = ((size_t)node * F + fcol) * 2;
      if (t == 0)      tabdst[idx]     = v + bf[fcol];
      else if (t == 1) tabdst[idx + 1] = v + bs[fcol];
      else if (t == 2) tabsrc16[idx]     = (unsigned short)f2bf(v);
      else             tabsrc16[idx + 1] = (unsigned short)f2bf(v);
    }
  }
}

// ---------------------------------------------------------------------------
// CSR build: count + scan
// ---------------------------------------------------------------------------
__global__ void count_deg(const int* __restrict__ dst, int* __restrict__ cnt, int E)
{
  int e = blockIdx.x * blockDim.x + threadIdx.x;
  if (e < E) atomicAdd(&cnt[dst[e]], 1);
}

__global__ __launch_bounds__(1024) void scan_k(
    const int* __restrict__ cnt, int* __restrict__ cursor, int N, int cpt)
{
  __shared__ int lds[1024];
  const int tid = threadIdx.x;
  const int base = tid * cpt;
  int run = 0;
  for (int j = 0; j < cpt; ++j) {
    int idx = base + j;
    run += (idx < N) ? cnt[idx] : 0;
  }
  lds[tid] = run;
  __syncthreads();
  for (int off = 1; off < 1024; off <<= 1) {
    int v = (tid >= off) ? lds[tid - off] : 0;
    __syncthreads();
    lds[tid] += v;
    __syncthreads();
  }
  int v = lds[tid] - run;
  for (int j = 0; j < cpt; ++j) {
    int idx = base + j;
    if (idx < N) { cursor[idx] = v; v += cnt[idx]; }
  }
}

// ---------------------------------------------------------------------------
// Aggregation: wave-pair per 64-edge chunk. ea staged to LDS asynchronously
// (global_load_lds), tabsrc gathers pipelined one 8-edge group ahead.
// r14: 8-edge group split into BRANCH-FREE phases (pd-load / term-compute /
// accumulate+flush) so the compiler interleaves the 8 independent FP chains
// — the dst-change branch previously serialized ~110-cyc chains per edge.
// NOTE: monolithic body on purpose — r11 lesson: factoring this into a
// helper taking the w2 array by pointer put w2/svc/svn/G8 into SCRATCH
// (FETCH 141MB -> 68GB, 60x slowdown). Keep arrays in kernel scope,
// constant-indexed. Never cap VGPRs below ~128 (r7 spill lesson).
// ---------------------------------------------------------------------------
__device__ __forceinline__ float sigm(float v) {
  return __builtin_amdgcn_rcpf(1.f + __expf(-v));
}
__device__ __forceinline__ float splus(float v) {
  return fmaxf(v, 0.f) + __logf(1.f + __expf(-fabsf(v)));
}

struct G8 { int4 a, b, c, d; };   // 8 edges of {src,dst}

__device__ __forceinline__ void gload(G8& g, const int4* p) {
  g.a = p[0]; g.b = p[1]; g.c = p[2]; g.d = p[3];
}
__device__ __forceinline__ void gather8(u32* sv, const G8& g,
                                        const u32* __restrict__ tabsrc, u32 f) {
  sv[0] = tabsrc[(u32)g.a.x * F + f]; sv[1] = tabsrc[(u32)g.a.z * F + f];
  sv[2] = tabsrc[(u32)g.b.x * F + f]; sv[3] = tabsrc[(u32)g.b.z * F + f];
  sv[4] = tabsrc[(u32)g.c.x * F + f]; sv[5] = tabsrc[(u32)g.c.z * F + f];
  sv[6] = tabsrc[(u32)g.d.x * F + f]; sv[7] = tabsrc[(u32)g.d.z * F + f];
}
__device__ __forceinline__ void dsts8(int* d, const G8& g) {
  d[0] = g.a.y; d[1] = g.a.w; d[2] = g.b.y; d[3] = g.b.w;
  d[4] = g.c.y; d[5] = g.c.w; d[6] = g.d.y; d[7] = g.d.w;
}

#define AS1 __attribute__((address_space(1)))
#define AS3 __attribute__((address_space(3)))
__device__ __forceinline__ void stage4k(const float4* g, float4* l, int lane) {
  __builtin_amdgcn_global_load_lds((AS1 const void*)(g + lane),       (AS3 void*)(l),       16, 0, 0);
  __builtin_amdgcn_global_load_lds((AS1 const void*)(g + 64 + lane),  (AS3 void*)(l + 64),  16, 0, 0);
  __builtin_amdgcn_global_load_lds((AS1 const void*)(g + 128 + lane), (AS3 void*)(l + 128), 16, 0, 0);
  __builtin_amdgcn_global_load_lds((AS1 const void*)(g + 192 + lane), (AS3 void*)(l + 192), 16, 0, 0);
}

__global__ __launch_bounds__(256, 4) void aggregate_lds(
    const float* __restrict__ tabdst, const u32* __restrict__ tabsrc,
    const float4* __restrict__ eap4, const int4* __restrict__ sd4,
    const float* __restrict__ Wf, const float* __restrict__ Ws,
    float* __restrict__ agg, int E)
{
  __shared__ float4 eabuf[2][256];         // 2 pairs x 64 edges x 64B = 8KB
  const int tid  = threadIdx.x;
  const int lane = tid & 63;
  const int wib  = tid >> 6;               // 0..3
  const int pair = wib >> 1;               // 0..1
  const int half = wib & 1;
  const int chunk = blockIdx.x * 2 + pair;
  const int p0 = chunk * CHK;
  const u32 f = (u32)((half << 6) | lane);

  // per-feature ea weights, packed {wf, ws}
  v2f w2[16];
  #pragma unroll
  for (int q = 0; q < 4; ++q) {
    float4 a = ((const float4*)(Wf + (size_t)f * ZD + 2 * F))[q];
    float4 b = ((const float4*)(Ws + (size_t)f * ZD + 2 * F))[q];
    w2[4*q+0] = (v2f){a.x, b.x};
    w2[4*q+1] = (v2f){a.y, b.y};
    w2[4*q+2] = (v2f){a.z, b.z};
    w2[4*q+3] = (v2f){a.w, b.w};
  }

  float4* lb0 = &eabuf[pair][0];
  if (half == 0) stage4k(eap4 + (size_t)p0 * 4, lb0, lane);  // async ea chunk

  const int sdb = p0 >> 1;                 // int4 index; group g at sdb + g*4
  G8 cur, nxt;
  gload(cur, sd4 + sdb);                   // group 0
  u32 svc[8];
  gather8(svc, cur, tabsrc, f);            // gathers group 0
  int dc[8];
  dsts8(dc, cur);
  gload(nxt, sd4 + sdb + 4);               // group 1

  int curDst = dc[0];
  float acc = 0.f;
  const int lim = E - p0;                  // valid-edge bound within chunk

  __syncthreads();                         // ea staged (vmcnt drained by producer)

  #pragma unroll
  for (int it = 0; it < 8; ++it) {
    // pipeline: gathers for group it+1, sd for group it+2
    u32 svn[8];
    gather8(svn, nxt, tabsrc, f);
    int dn[8];
    dsts8(dn, nxt);
    gload(nxt, sd4 + sdb + (it + 2) * 4);  // pad-covered beyond chunk

    const float4* lb = lb0 + it * 32;

    // phase 1: per-edge dst-table values (independent 8B loads, L1-hit heavy)
    v2f pd[8];
    #pragma unroll
    for (int i = 0; i < 8; ++i)
      pd[i] = *(const v2f*)(tabdst + (u32)dc[i] * 256u + 2u * f);

    // phase 2: branch-free term computation — 8 independent FP chains
    float term[8];
    #pragma unroll
    for (int i = 0; i < 8; ++i) {
      float4 q0 = lb[i*4+0], q1 = lb[i*4+1], q2 = lb[i*4+2], q3 = lb[i*4+3];
      u32 pk = svc[i];
      v2f a2 = pd[i] + (v2f){__uint_as_float(pk << 16),
                             __uint_as_float(pk & 0xFFFF0000u)};
      a2 += w2[0]  * q0.x; a2 += w2[1]  * q0.y; a2 += w2[2]  * q0.z; a2 += w2[3]  * q0.w;
      a2 += w2[4]  * q1.x; a2 += w2[5]  * q1.y; a2 += w2[6]  * q1.z; a2 += w2[7]  * q1.w;
      a2 += w2[8]  * q2.x; a2 += w2[9]  * q2.y; a2 += w2[10] * q2.z; a2 += w2[11] * q2.w;
      a2 += w2[12] * q3.x; a2 += w2[13] * q3.y; a2 += w2[14] * q3.z; a2 += w2[15] * q3.w;
      float tv = sigm(a2.x) * splus(a2.y);
      term[i] = ((it * 8 + i) < lim) ? tv : 0.f;
    }

    // phase 3: accumulate + rare wave-uniform flush (no FP chains inside)
    #pragma unroll
    for (int i = 0; i < 8; ++i) {
      int d = dc[i];
      if (d != curDst) {
        atomicAdd(&agg[(u32)curDst * F + f], acc);
        acc = 0.f; curDst = d;
      }
      acc += term[i];
    }

    #pragma unroll
    for (int i = 0; i < 8; ++i) { svc[i] = svn[i]; dc[i] = dn[i]; }
  }
  atomicAdd(&agg[(u32)curDst * F + f], acc);
}

// ---------------------------------------------------------------------------
__global__ __launch_bounds__(256) void bn_stats(
    const float* __restrict__ agg, float* __restrict__ sums, int N)
{
  const int f = threadIdx.x & 127;
  const int h = threadIdx.x >> 7;
  float s = 0.f, ss = 0.f;
  for (int r = blockIdx.x * 2 + h; r < N; r += gridDim.x * 2) {
    float v = agg[(size_t)r * F + f];
    s += v; ss += v * v;
  }
  atomicAdd(&sums[f], s);
  atomicAdd(&sums[F + f], ss);
}

__global__ __launch_bounds__(256) void finalize(
    const float* __restrict__ x, float* __restrict__ out,
    const float* __restrict__ sums, const float* __restrict__ bng,
    const float* __restrict__ bnb, const float* __restrict__ lng,
    const float* __restrict__ lnb, int N)
{
  const int lane = threadIdx.x & 63;
  const int wid  = (blockIdx.x * blockDim.x + threadIdx.x) >> 6;
  const int nwav = (gridDim.x * blockDim.x) >> 6;
  const int f0 = lane, f1 = lane + 64;
  const float invN = 1.f / (float)N;

  float mu0 = sums[f0] * invN, vv0 = sums[F + f0] * invN - mu0 * mu0;
  float mu1 = sums[f1] * invN, vv1 = sums[F + f1] * invN - mu1 * mu1;
  float sc0 = rsqrtf(vv0 + EPS) * bng[f0], sh0 = bnb[f0] - mu0 * sc0;
  float sc1 = rsqrtf(vv1 + EPS) * bng[f1], sh1 = bnb[f1] - mu1 * sc1;
  float g0 = lng[f0], g1 = lng[f1], be0 = lnb[f0], be1 = lnb[f1];

  for (int node = wid; node < N; node += nwav) {
    const size_t b = (size_t)node * F;
    float x0 = x[b + f0], x1 = x[b + f1];
    float h0 = out[b + f0] * sc0 + sh0 + x0;
    float h1 = out[b + f1] * sc1 + sh1 + x1;
    float s = h0 + h1, q = h0 * h0 + h1 * h1;
    #pragma unroll
    for (int o = 32; o > 0; o >>= 1) {
      s += __shfl_xor(s, o, 64);
      q += __shfl_xor(q, o, 64);
    }
    float mu = s * (1.f / 128.f);
    float var = q * (1.f / 128.f) - mu * mu;
    float rs = rsqrtf(var + EPS);
    float y0 = fmaxf((h0 - mu) * rs * g0 + be0, 0.f) + x0;
    float y1 = fmaxf((h1 - mu) * rs * g1 + be1, 0.f) + x1;
    out[b + f0] = y0;
    out[b + f1] = y1;
  }
}

// ---------------------------------------------------------------------------
extern "C" void kernel_launch(void* const* d_in, const int* in_sizes, int n_in,
                              void* d_out, int out_size, void* d_ws, size_t ws_size,
                              hipStream_t stream)
{
  const float* x   = (const float*)d_in[0];
  const int*   ei  = (const int*)d_in[1];
  const float* ea  = (const float*)d_in[2];
  const float* Wf  = (const float*)d_in[3];
  const float* bf  = (const float*)d_in[4];
  const float* Ws  = (const float*)d_in[5];
  const float* bs  = (const float*)d_in[6];
  const float* bng = (const float*)d_in[7];
  const float* bnb = (const float*)d_in[8];
  const float* lng = (const float*)d_in[9];
  const float* lnb = (const float*)d_in[10];

  const int N = in_sizes[0] / F;
  const int E = in_sizes[1] / 2;
  const int* srcA = ei;
  const int* dstA = ei + E;
  float* out = (float*)d_out;

  const int chunks = (E + CHK - 1) / CHK;
  const int chunksEven = (chunks + 1) & ~1;
  const int Epad = chunksEven * CHK + 128;   // sd lookahead + stage pad

  char* w = (char*)d_ws;
  size_t off = 0;
  auto up = [](size_t v) { return (v + 255) & ~(size_t)255; };
  float*  tabdst = (float*)(w + off);  off = up(off + (size_t)N * 256 * sizeof(float));
  u32*    tabsrc = (u32*)(w + off);    off = up(off + (size_t)N * F * sizeof(u32));
  int2*   sd     = (int2*)(w + off);   off = up(off + (size_t)Epad * sizeof(int2));
  int*    cursor = (int*)(w + off);    off = up(off + (size_t)N * sizeof(int));
  int*    cnt    = (int*)(w + off);    size_t cntOff = off;
                                       off = up(off + (size_t)N * sizeof(int));
  float*  sums   = (float*)(w + off);  size_t sumsEnd = off + 256 * sizeof(float);
                                       off = up(sumsEnd);
  float*  eap    = (float*)(w + off);  off = up(off + (size_t)Epad * EDIM * sizeof(float));

  // cnt and sums are adjacent -> one memset covers both
  hipMemsetAsync(cnt, 0, sumsEnd - cntOff, stream);
  hipMemsetAsync(sd + E, 0, (size_t)(Epad - E) * sizeof(int2), stream);
  hipMemsetAsync(eap + (size_t)E * EDIM, 0,
                 (size_t)(Epad - E) * EDIM * sizeof(float), stream);
  hipMemsetAsync(out, 0, (size_t)N * F * sizeof(float), stream);

  count_deg<<<(E + 255) / 256, 256, 0, stream>>>(dstA, cnt, E);
  const int cpt = (N + 1023) / 1024;
  scan_k<<<1, 1024, 0, stream>>>(cnt, cursor, N, cpt);

  // fused: gemm (even blocks) || csr-fill (odd blocks)
  const int gB = ((N + 63) / 64) * 8;
  const int fB = (E + 255) / 256;
  const int fusedGrid = 2 * (gB > fB ? gB : fB);
  gemm_fill<<<fusedGrid, 256, 0, stream>>>(
      x, Wf, Ws, bf, bs, tabdst, (unsigned short*)tabsrc, N,
      dstA, srcA, ea, cursor, sd, eap, E, gB, fB);

  aggregate_lds<<<chunksEven / 2, 256, 0, stream>>>(
      tabdst, tabsrc, (const float4*)eap, (const int4*)sd, Wf, Ws, out, E);

  bn_stats<<<256, 256, 0, stream>>>(out, sums, N);
  finalize<<<(N + 3) / 4, 256, 0, stream>>>(x, out, sums, bng, bnb, lng, lnb, N);
}

// Round 15
// 325.801 us; speedup vs baseline: 4.2878x; 4.2878x over previous
//
#include <hip/hip_runtime.h>
#include <math.h>

#define F 128
#define ZD 272
#define EDIM 16
#define EPS 1e-5f
#define CHK 64           // edges per chunk (one wave-pair)

typedef unsigned int u32;
typedef float v2f __attribute__((ext_vector_type(2)));

__device__ __forceinline__ u32 f2bf(float a) {
  u32 u = __float_as_uint(a);
  u += 0x7FFF + ((u >> 16) & 1);   // RNE
  return u >> 16;
}

// ---------------------------------------------------------------------------
// Fused kernel: node-table GEMM (even blocks) || CSR fill (odd blocks).
//   tabdst[n][f] = float2 {dst-filter(+bf), dst-softplus(+bs)} interleaved f32
//   tabsrc[n][f] = u32 {bf16 srcF | bf16 srcS<<16}, halves written directly
// ---------------------------------------------------------------------------
__global__ __launch_bounds__(256) void gemm_fill(
    const float* __restrict__ x, const float* __restrict__ Wf,
    const float* __restrict__ Ws, const float* __restrict__ bf,
    const float* __restrict__ bs, float* __restrict__ tabdst,
    unsigned short* __restrict__ tabsrc16, int N,
    const int* __restrict__ dst, const int* __restrict__ srcA,
    const float* __restrict__ ea, int* __restrict__ cursor,
    int2* __restrict__ sd, float* __restrict__ eap, int E,
    int gB, int fB)
{
  __shared__ float As[64][76];  // [k][m]   (gemm role only)
  __shared__ float Bs[64][76];  // [k][n]
  const int b = blockIdx.x;
  const int tid = threadIdx.x;

  if ((b & 1) == 1) {
    // ---------------- fill role (odd blocks) ----------------
    const int b2 = b >> 1;
    if (b2 >= fB) return;
    int e = b2 * 256 + tid;
    if (e < E) {
      int d = dst[e];
      int pos = atomicAdd(&cursor[d], 1);
      sd[pos] = make_int2(srcA[e], d);
      const float4* s4 = (const float4*)(ea + (size_t)e * EDIM);
      float4 a = s4[0], bb = s4[1], c = s4[2], dd = s4[3];
      float4* d4 = (float4*)(eap + (size_t)pos * EDIM);
      d4[0] = a; d4[1] = bb; d4[2] = c; d4[3] = dd;
    }
    return;
  }

  // ---------------- gemm role (even blocks) ----------------
  const int b2 = b >> 1;
  if (b2 >= gB) return;
  const int bm = b2 >> 3, bn = b2 & 7;
  const int t = bn >> 1;                 // 0..3
  const int fbase = (bn & 1) * 64;       // 0 or 64
  const float* W = (t & 1) ? Ws : Wf;
  const int koff = (t >= 2) ? F : 0;
  const int kq = (tid & 15) * 4;
  const int rr = tid >> 4;

  const int tx = tid & 15, ty = tid >> 4;
  const int m0 = ty * 4, n0 = tx * 4;
  float acc[4][4] = {};

  for (int kk = 0; kk < F; kk += 64) {
    #pragma unroll
    for (int it = 0; it < 4; ++it) {
      int row = it * 16 + rr;
      int node = bm * 64 + row;
      float4 v = make_float4(0.f, 0.f, 0.f, 0.f);
      if (node < N) v = *(const float4*)(x + (size_t)node * F + kk + kq);
      As[kq + 0][row] = v.x; As[kq + 1][row] = v.y;
      As[kq + 2][row] = v.z; As[kq + 3][row] = v.w;
    }
    #pragma unroll
    for (int it = 0; it < 4; ++it) {
      int n = it * 16 + rr;
      float4 v = *(const float4*)(W + (size_t)(fbase + n) * ZD + koff + kk + kq);
      Bs[kq + 0][n] = v.x; Bs[kq + 1][n] = v.y;
      Bs[kq + 2][n] = v.z; Bs[kq + 3][n] = v.w;
    }
    __syncthreads();
    #pragma unroll 8
    for (int k = 0; k < 64; ++k) {
      float4 a = *(const float4*)&As[k][m0];
      float4 bb = *(const float4*)&Bs[k][n0];
      float av[4] = {a.x, a.y, a.z, a.w};
      float bv[4] = {bb.x, bb.y, bb.z, bb.w};
      #pragma unroll
      for (int i = 0; i < 4; ++i)
        #pragma unroll
        for (int j = 0; j < 4; ++j)
          acc[i][j] += av[i] * bv[j];
    }
    __syncthreads();
  }

  #pragma unroll
  for (int i = 0; i < 4; ++i) {
    int node = bm * 64 + m0 + i;
    if (node >= N) continue;
    #pragma unroll
    for (int j = 0; j < 4; ++j) {
      int fcol = fbase + n0 + j;
      float v = acc[i][j];
      size_t idx = ((size_t)node * F + fcol) * 2;
      if (t == 0)      tabdst[idx]     = v + bf[fcol];
      else if (t == 1) tabdst[idx + 1] = v + bs[fcol];
      else if (t == 2) tabsrc16[idx]     = (unsigned short)f2bf(v);
      else             tabsrc16[idx + 1] = (unsigned short)f2bf(v);
    }
  }
}

// ---------------------------------------------------------------------------
// CSR build: count + scan
// ---------------------------------------------------------------------------
__global__ void count_deg(const int* __restrict__ dst, int* __restrict__ cnt, int E)
{
  int e = blockIdx.x * blockDim.x + threadIdx.x;
  if (e < E) atomicAdd(&cnt[dst[e]], 1);
}

__global__ __launch_bounds__(1024) void scan_k(
    const int* __restrict__ cnt, int* __restrict__ cursor, int N, int cpt)
{
  __shared__ int lds[1024];
  const int tid = threadIdx.x;
  const int base = tid * cpt;
  int run = 0;
  for (int j = 0; j < cpt; ++j) {
    int idx = base + j;
    run += (idx < N) ? cnt[idx] : 0;
  }
  lds[tid] = run;
  __syncthreads();
  for (int off = 1; off < 1024; off <<= 1) {
    int v = (tid >= off) ? lds[tid - off] : 0;
    __syncthreads();
    lds[tid] += v;
    __syncthreads();
  }
  int v = lds[tid] - run;
  for (int j = 0; j < cpt; ++j) {
    int idx = base + j;
    if (idx < N) { cursor[idx] = v; v += cnt[idx]; }
  }
}

// ---------------------------------------------------------------------------
// Aggregation: wave-pair per 64-edge chunk. ea staged to LDS asynchronously
// (global_load_lds), tabsrc gathers pipelined one 8-edge group ahead.
// r15: 2-edge pairing — pd loaded per edge (breaks the loop-carried pdfs
// dependency), two independent FP chains computed straight-line, branchy
// accumulate holds only adds. Peak liveness +~20 VGPR vs r6 (fits 128 cap;
// r14's 8-edge batching demanded ~140 -> spilled to scratch, 8.6x slower).
// NOTE: monolithic body on purpose — r11 lesson: helper taking w2 by pointer
// put everything in SCRATCH. Keep arrays kernel-scope, constant-indexed.
// Never cap VGPRs below ~128 (r7 lesson).
// ---------------------------------------------------------------------------
__device__ __forceinline__ float sigm(float v) {
  return __builtin_amdgcn_rcpf(1.f + __expf(-v));
}
__device__ __forceinline__ float splus(float v) {
  return fmaxf(v, 0.f) + __logf(1.f + __expf(-fabsf(v)));
}

struct G8 { int4 a, b, c, d; };   // 8 edges of {src,dst}

__device__ __forceinline__ void gload(G8& g, const int4* p) {
  g.a = p[0]; g.b = p[1]; g.c = p[2]; g.d = p[3];
}
__device__ __forceinline__ void gather8(u32* sv, const G8& g,
                                        const u32* __restrict__ tabsrc, u32 f) {
  sv[0] = tabsrc[(u32)g.a.x * F + f]; sv[1] = tabsrc[(u32)g.a.z * F + f];
  sv[2] = tabsrc[(u32)g.b.x * F + f]; sv[3] = tabsrc[(u32)g.b.z * F + f];
  sv[4] = tabsrc[(u32)g.c.x * F + f]; sv[5] = tabsrc[(u32)g.c.z * F + f];
  sv[6] = tabsrc[(u32)g.d.x * F + f]; sv[7] = tabsrc[(u32)g.d.z * F + f];
}
__device__ __forceinline__ void dsts8(int* d, const G8& g) {
  d[0] = g.a.y; d[1] = g.a.w; d[2] = g.b.y; d[3] = g.b.w;
  d[4] = g.c.y; d[5] = g.c.w; d[6] = g.d.y; d[7] = g.d.w;
}

#define AS1 __attribute__((address_space(1)))
#define AS3 __attribute__((address_space(3)))
__device__ __forceinline__ void stage4k(const float4* g, float4* l, int lane) {
  __builtin_amdgcn_global_load_lds((AS1 const void*)(g + lane),       (AS3 void*)(l),       16, 0, 0);
  __builtin_amdgcn_global_load_lds((AS1 const void*)(g + 64 + lane),  (AS3 void*)(l + 64),  16, 0, 0);
  __builtin_amdgcn_global_load_lds((AS1 const void*)(g + 128 + lane), (AS3 void*)(l + 128), 16, 0, 0);
  __builtin_amdgcn_global_load_lds((AS1 const void*)(g + 192 + lane), (AS3 void*)(l + 192), 16, 0, 0);
}

__global__ __launch_bounds__(256, 4) void aggregate_lds(
    const float* __restrict__ tabdst, const u32* __restrict__ tabsrc,
    const float4* __restrict__ eap4, const int4* __restrict__ sd4,
    const float* __restrict__ Wf, const float* __restrict__ Ws,
    float* __restrict__ agg, int E)
{
  __shared__ float4 eabuf[2][256];         // 2 pairs x 64 edges x 64B = 8KB
  const int tid  = threadIdx.x;
  const int lane = tid & 63;
  const int wib  = tid >> 6;               // 0..3
  const int pair = wib >> 1;               // 0..1
  const int half = wib & 1;
  const int chunk = blockIdx.x * 2 + pair;
  const int p0 = chunk * CHK;
  const u32 f = (u32)((half << 6) | lane);

  // per-feature ea weights, packed {wf, ws}
  v2f w2[16];
  #pragma unroll
  for (int q = 0; q < 4; ++q) {
    float4 a = ((const float4*)(Wf + (size_t)f * ZD + 2 * F))[q];
    float4 b = ((const float4*)(Ws + (size_t)f * ZD + 2 * F))[q];
    w2[4*q+0] = (v2f){a.x, b.x};
    w2[4*q+1] = (v2f){a.y, b.y};
    w2[4*q+2] = (v2f){a.z, b.z};
    w2[4*q+3] = (v2f){a.w, b.w};
  }

  float4* lb0 = &eabuf[pair][0];
  if (half == 0) stage4k(eap4 + (size_t)p0 * 4, lb0, lane);  // async ea chunk

  const int sdb = p0 >> 1;                 // int4 index; group g at sdb + g*4
  G8 cur, nxt;
  gload(cur, sd4 + sdb);                   // group 0
  u32 svc[8];
  gather8(svc, cur, tabsrc, f);            // gathers group 0
  int dc[8];
  dsts8(dc, cur);
  gload(nxt, sd4 + sdb + 4);               // group 1

  int curDst = dc[0];
  float acc = 0.f;
  const int lim = E - p0;                  // valid-edge bound within chunk

  __syncthreads();                         // ea staged (vmcnt drained by producer)

  #pragma unroll
  for (int it = 0; it < 8; ++it) {
    // pipeline: gathers for group it+1, sd for group it+2
    u32 svn[8];
    gather8(svn, nxt, tabsrc, f);
    int dn[8];
    dsts8(dn, nxt);
    gload(nxt, sd4 + sdb + (it + 2) * 4);  // pad-covered beyond chunk

    const float4* lb = lb0 + it * 32;

    #pragma unroll
    for (int pr = 0; pr < 4; ++pr) {
      const int ia = 2 * pr, ib = 2 * pr + 1;
      const int da = dc[ia], db = dc[ib];
      // independent pd loads (mostly same-dst -> L1 broadcast hits)
      v2f pda = *(const v2f*)(tabdst + (u32)da * 256u + 2u * f);
      v2f pdb = *(const v2f*)(tabdst + (u32)db * 256u + 2u * f);
      // two independent FP chains, straight-line (compiler interleaves)
      float4 aq0 = lb[ia*4+0], aq1 = lb[ia*4+1], aq2 = lb[ia*4+2], aq3 = lb[ia*4+3];
      float4 bq0 = lb[ib*4+0], bq1 = lb[ib*4+1], bq2 = lb[ib*4+2], bq3 = lb[ib*4+3];
      u32 pka = svc[ia], pkb = svc[ib];
      v2f aa = pda + (v2f){__uint_as_float(pka << 16),
                           __uint_as_float(pka & 0xFFFF0000u)};
      v2f ab = pdb + (v2f){__uint_as_float(pkb << 16),
                           __uint_as_float(pkb & 0xFFFF0000u)};
      aa += w2[0]  * aq0.x; ab += w2[0]  * bq0.x;
      aa += w2[1]  * aq0.y; ab += w2[1]  * bq0.y;
      aa += w2[2]  * aq0.z; ab += w2[2]  * bq0.z;
      aa += w2[3]  * aq0.w; ab += w2[3]  * bq0.w;
      aa += w2[4]  * aq1.x; ab += w2[4]  * bq1.x;
      aa += w2[5]  * aq1.y; ab += w2[5]  * bq1.y;
      aa += w2[6]  * aq1.z; ab += w2[6]  * bq1.z;
      aa += w2[7]  * aq1.w; ab += w2[7]  * bq1.w;
      aa += w2[8]  * aq2.x; ab += w2[8]  * bq2.x;
      aa += w2[9]  * aq2.y; ab += w2[9]  * bq2.y;
      aa += w2[10] * aq2.z; ab += w2[10] * bq2.z;
      aa += w2[11] * aq2.w; ab += w2[11] * bq2.w;
      aa += w2[12] * aq3.x; ab += w2[12] * bq3.x;
      aa += w2[13] * aq3.y; ab += w2[13] * bq3.y;
      aa += w2[14] * aq3.z; ab += w2[14] * bq3.z;
      aa += w2[15] * aq3.w; ab += w2[15] * bq3.w;
      float ta = sigm(aa.x) * splus(aa.y);
      float tb = sigm(ab.x) * splus(ab.y);
      ta = ((it * 8 + ia) < lim) ? ta : 0.f;
      tb = ((it * 8 + ib) < lim) ? tb : 0.f;
      // accumulate + rare wave-uniform flush (adds only)
      if (da != curDst) {
        atomicAdd(&agg[(u32)curDst * F + f], acc);
        acc = 0.f; curDst = da;
      }
      acc += ta;
      if (db != curDst) {
        atomicAdd(&agg[(u32)curDst * F + f], acc);
        acc = 0.f; curDst = db;
      }
      acc += tb;
    }

    #pragma unroll
    for (int i = 0; i < 8; ++i) { svc[i] = svn[i]; dc[i] = dn[i]; }
  }
  atomicAdd(&agg[(u32)curDst * F + f], acc);
}

// ---------------------------------------------------------------------------
__global__ __launch_bounds__(256) void bn_stats(
    const float* __restrict__ agg, float* __restrict__ sums, int N)
{
  const int f = threadIdx.x & 127;
  const int h = threadIdx.x >> 7;
  float s = 0.f, ss = 0.f;
  for (int r = blockIdx.x * 2 + h; r < N; r += gridDim.x * 2) {
    float v = agg[(size_t)r * F + f];
    s += v; ss += v * v;
  }
  atomicAdd(&sums[f], s);
  atomicAdd(&sums[F + f], ss);
}

__global__ __launch_bounds__(256) void finalize(
    const float* __restrict__ x, float* __restrict__ out,
    const float* __restrict__ sums, const float* __restrict__ bng,
    const float* __restrict__ bnb, const float* __restrict__ lng,
    const float* __restrict__ lnb, int N)
{
  const int lane = threadIdx.x & 63;
  const int wid  = (blockIdx.x * blockDim.x + threadIdx.x) >> 6;
  const int nwav = (gridDim.x * blockDim.x) >> 6;
  const int f0 = lane, f1 = lane + 64;
  const float invN = 1.f / (float)N;

  float mu0 = sums[f0] * invN, vv0 = sums[F + f0] * invN - mu0 * mu0;
  float mu1 = sums[f1] * invN, vv1 = sums[F + f1] * invN - mu1 * mu1;
  float sc0 = rsqrtf(vv0 + EPS) * bng[f0], sh0 = bnb[f0] - mu0 * sc0;
  float sc1 = rsqrtf(vv1 + EPS) * bng[f1], sh1 = bnb[f1] - mu1 * sc1;
  float g0 = lng[f0], g1 = lng[f1], be0 = lnb[f0], be1 = lnb[f1];

  for (int node = wid; node < N; node += nwav) {
    const size_t b = (size_t)node * F;
    float x0 = x[b + f0], x1 = x[b + f1];
    float h0 = out[b + f0] * sc0 + sh0 + x0;
    float h1 = out[b + f1] * sc1 + sh1 + x1;
    float s = h0 + h1, q = h0 * h0 + h1 * h1;
    #pragma unroll
    for (int o = 32; o > 0; o >>= 1) {
      s += __shfl_xor(s, o, 64);
      q += __shfl_xor(q, o, 64);
    }
    float mu = s * (1.f / 128.f);
    float var = q * (1.f / 128.f) - mu * mu;
    float rs = rsqrtf(var + EPS);
    float y0 = fmaxf((h0 - mu) * rs * g0 + be0, 0.f) + x0;
    float y1 = fmaxf((h1 - mu) * rs * g1 + be1, 0.f) + x1;
    out[b + f0] = y0;
    out[b + f1] = y1;
  }
}

// ---------------------------------------------------------------------------
extern "C" void kernel_launch(void* const* d_in, const int* in_sizes, int n_in,
                              void* d_out, int out_size, void* d_ws, size_t ws_size,
                              hipStream_t stream)
{
  const float* x   = (const float*)d_in[0];
  const int*   ei  = (const int*)d_in[1];
  const float* ea  = (const float*)d_in[2];
  const float* Wf  = (const float*)d_in[3];
  const float* bf  = (const float*)d_in[4];
  const float* Ws  = (const float*)d_in[5];
  const float* bs  = (const float*)d_in[6];
  const float* bng = (const float*)d_in[7];
  const float* bnb = (const float*)d_in[8];
  const float* lng = (const float*)d_in[9];
  const float* lnb = (const float*)d_in[10];

  const int N = in_sizes[0] / F;
  const int E = in_sizes[1] / 2;
  const int* srcA = ei;
  const int* dstA = ei + E;
  float* out = (float*)d_out;

  const int chunks = (E + CHK - 1) / CHK;
  const int chunksEven = (chunks + 1) & ~1;
  const int Epad = chunksEven * CHK + 128;   // sd lookahead + stage pad

  char* w = (char*)d_ws;
  size_t off = 0;
  auto up = [](size_t v) { return (v + 255) & ~(size_t)255; };
  float*  tabdst = (float*)(w + off);  off = up(off + (size_t)N * 256 * sizeof(float));
  u32*    tabsrc = (u32*)(w + off);    off = up(off + (size_t)N * F * sizeof(u32));
  int2*   sd     = (int2*)(w + off);   off = up(off + (size_t)Epad * sizeof(int2));
  int*    cursor = (int*)(w + off);    off = up(off + (size_t)N * sizeof(int));
  int*    cnt    = (int*)(w + off);    size_t cntOff = off;
                                       off = up(off + (size_t)N * sizeof(int));
  float*  sums   = (float*)(w + off);  size_t sumsEnd = off + 256 * sizeof(float);
                                       off = up(sumsEnd);
  float*  eap    = (float*)(w + off);  off = up(off + (size_t)Epad * EDIM * sizeof(float));

  // cnt and sums are adjacent -> one memset covers both
  hipMemsetAsync(cnt, 0, sumsEnd - cntOff, stream);
  hipMemsetAsync(sd + E, 0, (size_t)(Epad - E) * sizeof(int2), stream);
  hipMemsetAsync(eap + (size_t)E * EDIM, 0,
                 (size_t)(Epad - E) * EDIM * sizeof(float), stream);
  hipMemsetAsync(out, 0, (size_t)N * F * sizeof(float), stream);

  count_deg<<<(E + 255) / 256, 256, 0, stream>>>(dstA, cnt, E);
  const int cpt = (N + 1023) / 1024;
  scan_k<<<1, 1024, 0, stream>>>(cnt, cursor, N, cpt);

  // fused: gemm (even blocks) || csr-fill (odd blocks)
  const int gB = ((N + 63) / 64) * 8;
  const int fB = (E + 255) / 256;
  const int fusedGrid = 2 * (gB > fB ? gB : fB);
  gemm_fill<<<fusedGrid, 256, 0, stream>>>(
      x, Wf, Ws, bf, bs, tabdst, (unsigned short*)tabsrc, N,
      dstA, srcA, ea, cursor, sd, eap, E, gB, fB);

  aggregate_lds<<<chunksEven / 2, 256, 0, stream>>>(
      tabdst, tabsrc, (const float4*)eap, (const int4*)sd, Wf, Ws, out, E);

  bn_stats<<<256, 256, 0, stream>>>(out, sums, N);
  finalize<<<(N + 3) / 4, 256, 0, stream>>>(x, out, sums, bng, bnb, lng, lnb, N);
}

// Round 16
// 310.776 us; speedup vs baseline: 4.4951x; 1.0483x over previous
//
#include <hip/hip_runtime.h>
#include <math.h>

#define F 128
#define ZD 272
#define EDIM 16
#define EPS 1e-5f
#define CHK 64           // edges per chunk (one wave-pair)

typedef unsigned int u32;
typedef float v2f __attribute__((ext_vector_type(2)));

__device__ __forceinline__ u32 f2bf(float a) {
  u32 u = __float_as_uint(a);
  u += 0x7FFF + ((u >> 16) & 1);   // RNE
  return u >> 16;
}

// ---------------------------------------------------------------------------
// Fused kernel: node-table GEMM (even blocks) || CSR fill (odd blocks).
//   tabdst[n][f] = float2 {dst-filter(+bf), dst-softplus(+bs)} interleaved f32
//   tabsrc[n][f] = u32 {bf16 srcF | bf16 srcS<<16}, halves written directly
// ---------------------------------------------------------------------------
__global__ __launch_bounds__(256) void gemm_fill(
    const float* __restrict__ x, const float* __restrict__ Wf,
    const float* __restrict__ Ws, const float* __restrict__ bf,
    const float* __restrict__ bs, float* __restrict__ tabdst,
    unsigned short* __restrict__ tabsrc16, int N,
    const int* __restrict__ dst, const int* __restrict__ srcA,
    const float* __restrict__ ea, int* __restrict__ cursor,
    int2* __restrict__ sd, float* __restrict__ eap, int E,
    int gB, int fB)
{
  __shared__ float As[64][76];  // [k][m]   (gemm role only)
  __shared__ float Bs[64][76];  // [k][n]
  const int b = blockIdx.x;
  const int tid = threadIdx.x;

  if ((b & 1) == 1) {
    // ---------------- fill role (odd blocks) ----------------
    const int b2 = b >> 1;
    if (b2 >= fB) return;
    int e = b2 * 256 + tid;
    if (e < E) {
      int d = dst[e];
      int pos = atomicAdd(&cursor[d], 1);
      sd[pos] = make_int2(srcA[e], d);
      const float4* s4 = (const float4*)(ea + (size_t)e * EDIM);
      float4 a = s4[0], bb = s4[1], c = s4[2], dd = s4[3];
      float4* d4 = (float4*)(eap + (size_t)pos * EDIM);
      d4[0] = a; d4[1] = bb; d4[2] = c; d4[3] = dd;
    }
    return;
  }

  // ---------------- gemm role (even blocks) ----------------
  const int b2 = b >> 1;
  if (b2 >= gB) return;
  const int bm = b2 >> 3, bn = b2 & 7;
  const int t = bn >> 1;                 // 0..3
  const int fbase = (bn & 1) * 64;       // 0 or 64
  const float* W = (t & 1) ? Ws : Wf;
  const int koff = (t >= 2) ? F : 0;
  const int kq = (tid & 15) * 4;
  const int rr = tid >> 4;

  const int tx = tid & 15, ty = tid >> 4;
  const int m0 = ty * 4, n0 = tx * 4;
  float acc[4][4] = {};

  for (int kk = 0; kk < F; kk += 64) {
    #pragma unroll
    for (int it = 0; it < 4; ++it) {
      int row = it * 16 + rr;
      int node = bm * 64 + row;
      float4 v = make_float4(0.f, 0.f, 0.f, 0.f);
      if (node < N) v = *(const float4*)(x + (size_t)node * F + kk + kq);
      As[kq + 0][row] = v.x; As[kq + 1][row] = v.y;
      As[kq + 2][row] = v.z; As[kq + 3][row] = v.w;
    }
    #pragma unroll
    for (int it = 0; it < 4; ++it) {
      int n = it * 16 + rr;
      float4 v = *(const float4*)(W + (size_t)(fbase + n) * ZD + koff + kk + kq);
      Bs[kq + 0][n] = v.x; Bs[kq + 1][n] = v.y;
      Bs[kq + 2][n] = v.z; Bs[kq + 3][n] = v.w;
    }
    __syncthreads();
    #pragma unroll 8
    for (int k = 0; k < 64; ++k) {
      float4 a = *(const float4*)&As[k][m0];
      float4 bb = *(const float4*)&Bs[k][n0];
      float av[4] = {a.x, a.y, a.z, a.w};
      float bv[4] = {bb.x, bb.y, bb.z, bb.w};
      #pragma unroll
      for (int i = 0; i < 4; ++i)
        #pragma unroll
        for (int j = 0; j < 4; ++j)
          acc[i][j] += av[i] * bv[j];
    }
    __syncthreads();
  }

  #pragma unroll
  for (int i = 0; i < 4; ++i) {
    int node = bm * 64 + m0 + i;
    if (node >= N) continue;
    #pragma unroll
    for (int j = 0; j < 4; ++j) {
      int fcol = fbase + n0 + j;
      float v = acc[i][j];
      size_t idx = ((size_t)node * F + fcol) * 2;
      if (t == 0)      tabdst[idx]     = v + bf[fcol];
      else if (t == 1) tabdst[idx + 1] = v + bs[fcol];
      else if (t == 2) tabsrc16[idx]     = (unsigned short)f2bf(v);
      else             tabsrc16[idx + 1] = (unsigned short)f2bf(v);
    }
  }
}

// ---------------------------------------------------------------------------
// CSR build: count + scan
// ---------------------------------------------------------------------------
__global__ void count_deg(const int* __restrict__ dst, int* __restrict__ cnt, int E)
{
  int e = blockIdx.x * blockDim.x + threadIdx.x;
  if (e < E) atomicAdd(&cnt[dst[e]], 1);
}

__global__ __launch_bounds__(1024) void scan_k(
    const int* __restrict__ cnt, int* __restrict__ cursor, int N, int cpt)
{
  __shared__ int lds[1024];
  const int tid = threadIdx.x;
  const int base = tid * cpt;
  int run = 0;
  for (int j = 0; j < cpt; ++j) {
    int idx = base + j;
    run += (idx < N) ? cnt[idx] : 0;
  }
  lds[tid] = run;
  __syncthreads();
  for (int off = 1; off < 1024; off <<= 1) {
    int v = (tid >= off) ? lds[tid - off] : 0;
    __syncthreads();
    lds[tid] += v;
    __syncthreads();
  }
  int v = lds[tid] - run;
  for (int j = 0; j < cpt; ++j) {
    int idx = base + j;
    if (idx < N) { cursor[idx] = v; v += cnt[idx]; }
  }
}

// ---------------------------------------------------------------------------
// Aggregation: ONE wave-pair per 64-edge chunk (128-thread blocks, r16).
// ea staged to LDS asynchronously (global_load_lds), tabsrc gathers
// pipelined one 8-edge group ahead. Inner body = r12's exact structure
// (fastest measured: 141 us; r15's 2-edge ILP pairing was slower).
// r16 change: block 256->128 threads, LDS 8KB->4KB — more independent
// blocks so the scheduler can pack more waves/CU (occupancy was 38%,
// per-SIMD issue only ~35% -> latency-bound on tabsrc L3 gathers).
// NOTE: monolithic body on purpose — r11 lesson: helper taking w2 by pointer
// put everything in SCRATCH. Keep arrays kernel-scope, constant-indexed.
// Never cap VGPRs below ~128 (r7 lesson; r14's 8-edge batching also spilled).
// ---------------------------------------------------------------------------
__device__ __forceinline__ float sigm(float v) {
  return __builtin_amdgcn_rcpf(1.f + __expf(-v));
}
__device__ __forceinline__ float splus(float v) {
  return fmaxf(v, 0.f) + __logf(1.f + __expf(-fabsf(v)));
}

struct G8 { int4 a, b, c, d; };   // 8 edges of {src,dst}

__device__ __forceinline__ void gload(G8& g, const int4* p) {
  g.a = p[0]; g.b = p[1]; g.c = p[2]; g.d = p[3];
}
__device__ __forceinline__ void gather8(u32* sv, const G8& g,
                                        const u32* __restrict__ tabsrc, u32 f) {
  sv[0] = tabsrc[(u32)g.a.x * F + f]; sv[1] = tabsrc[(u32)g.a.z * F + f];
  sv[2] = tabsrc[(u32)g.b.x * F + f]; sv[3] = tabsrc[(u32)g.b.z * F + f];
  sv[4] = tabsrc[(u32)g.c.x * F + f]; sv[5] = tabsrc[(u32)g.c.z * F + f];
  sv[6] = tabsrc[(u32)g.d.x * F + f]; sv[7] = tabsrc[(u32)g.d.z * F + f];
}
__device__ __forceinline__ void dsts8(int* d, const G8& g) {
  d[0] = g.a.y; d[1] = g.a.w; d[2] = g.b.y; d[3] = g.b.w;
  d[4] = g.c.y; d[5] = g.c.w; d[6] = g.d.y; d[7] = g.d.w;
}

#define AS1 __attribute__((address_space(1)))
#define AS3 __attribute__((address_space(3)))
__device__ __forceinline__ void stage4k(const float4* g, float4* l, int lane) {
  __builtin_amdgcn_global_load_lds((AS1 const void*)(g + lane),       (AS3 void*)(l),       16, 0, 0);
  __builtin_amdgcn_global_load_lds((AS1 const void*)(g + 64 + lane),  (AS3 void*)(l + 64),  16, 0, 0);
  __builtin_amdgcn_global_load_lds((AS1 const void*)(g + 128 + lane), (AS3 void*)(l + 128), 16, 0, 0);
  __builtin_amdgcn_global_load_lds((AS1 const void*)(g + 192 + lane), (AS3 void*)(l + 192), 16, 0, 0);
}

__global__ __launch_bounds__(128, 4) void aggregate_lds(
    const float* __restrict__ tabdst, const u32* __restrict__ tabsrc,
    const float4* __restrict__ eap4, const int4* __restrict__ sd4,
    const float* __restrict__ Wf, const float* __restrict__ Ws,
    float* __restrict__ agg, int E)
{
  __shared__ float4 eabuf[256];            // 64 edges x 64B = 4KB
  const int tid  = threadIdx.x;
  const int lane = tid & 63;
  const int half = tid >> 6;               // 0..1
  const int chunk = blockIdx.x;
  const int p0 = chunk * CHK;
  const u32 f = (u32)((half << 6) | lane);

  // per-feature ea weights, packed {wf, ws}
  v2f w2[16];
  #pragma unroll
  for (int q = 0; q < 4; ++q) {
    float4 a = ((const float4*)(Wf + (size_t)f * ZD + 2 * F))[q];
    float4 b = ((const float4*)(Ws + (size_t)f * ZD + 2 * F))[q];
    w2[4*q+0] = (v2f){a.x, b.x};
    w2[4*q+1] = (v2f){a.y, b.y};
    w2[4*q+2] = (v2f){a.z, b.z};
    w2[4*q+3] = (v2f){a.w, b.w};
  }

  float4* lb0 = &eabuf[0];
  if (half == 0) stage4k(eap4 + (size_t)p0 * 4, lb0, lane);  // async ea chunk

  const int sdb = p0 >> 1;                 // int4 index; group g at sdb + g*4
  G8 cur, nxt;
  gload(cur, sd4 + sdb);                   // group 0
  u32 svc[8];
  gather8(svc, cur, tabsrc, f);            // gathers group 0
  int dc[8];
  dsts8(dc, cur);
  gload(nxt, sd4 + sdb + 4);               // group 1

  int curDst = dc[0];
  v2f pdfs = *(const v2f*)(tabdst + (u32)curDst * 256u + 2u * f);
  float acc = 0.f;
  const int lim = E - p0;                  // valid-edge bound within chunk

  __syncthreads();                         // ea staged (vmcnt drained by producer)

  #pragma unroll
  for (int it = 0; it < 8; ++it) {
    // pipeline: gathers for group it+1, sd for group it+2
    u32 svn[8];
    gather8(svn, nxt, tabsrc, f);
    int dn[8];
    dsts8(dn, nxt);
    gload(nxt, sd4 + sdb + (it + 2) * 4);  // pad-covered beyond chunk

    const float4* lb = lb0 + it * 32;
    #pragma unroll
    for (int i = 0; i < 8; ++i) {
      int d = dc[i];
      if (d != curDst) {                   // value-uniform across wave
        atomicAdd(&agg[(u32)curDst * F + f], acc);
        acc = 0.f; curDst = d;
        pdfs = *(const v2f*)(tabdst + (u32)d * 256u + 2u * f);
      }
      float4 q0 = lb[i*4+0], q1 = lb[i*4+1], q2 = lb[i*4+2], q3 = lb[i*4+3];
      u32 pk = svc[i];
      v2f a2 = pdfs + (v2f){__uint_as_float(pk << 16),
                            __uint_as_float(pk & 0xFFFF0000u)};
      a2 += w2[0]  * q0.x; a2 += w2[1]  * q0.y; a2 += w2[2]  * q0.z; a2 += w2[3]  * q0.w;
      a2 += w2[4]  * q1.x; a2 += w2[5]  * q1.y; a2 += w2[6]  * q1.z; a2 += w2[7]  * q1.w;
      a2 += w2[8]  * q2.x; a2 += w2[9]  * q2.y; a2 += w2[10] * q2.z; a2 += w2[11] * q2.w;
      a2 += w2[12] * q3.x; a2 += w2[13] * q3.y; a2 += w2[14] * q3.z; a2 += w2[15] * q3.w;
      float term = sigm(a2.x) * splus(a2.y);
      acc += ((it * 8 + i) < lim) ? term : 0.f;
    }
    #pragma unroll
    for (int i = 0; i < 8; ++i) { svc[i] = svn[i]; dc[i] = dn[i]; }
  }
  atomicAdd(&agg[(u32)curDst * F + f], acc);
}

// ---------------------------------------------------------------------------
__global__ __launch_bounds__(256) void bn_stats(
    const float* __restrict__ agg, float* __restrict__ sums, int N)
{
  const int f = threadIdx.x & 127;
  const int h = threadIdx.x >> 7;
  float s = 0.f, ss = 0.f;
  for (int r = blockIdx.x * 2 + h; r < N; r += gridDim.x * 2) {
    float v = agg[(size_t)r * F + f];
    s += v; ss += v * v;
  }
  atomicAdd(&sums[f], s);
  atomicAdd(&sums[F + f], ss);
}

__global__ __launch_bounds__(256) void finalize(
    const float* __restrict__ x, float* __restrict__ out,
    const float* __restrict__ sums, const float* __restrict__ bng,
    const float* __restrict__ bnb, const float* __restrict__ lng,
    const float* __restrict__ lnb, int N)
{
  const int lane = threadIdx.x & 63;
  const int wid  = (blockIdx.x * blockDim.x + threadIdx.x) >> 6;
  const int nwav = (gridDim.x * blockDim.x) >> 6;
  const int f0 = lane, f1 = lane + 64;
  const float invN = 1.f / (float)N;

  float mu0 = sums[f0] * invN, vv0 = sums[F + f0] * invN - mu0 * mu0;
  float mu1 = sums[f1] * invN, vv1 = sums[F + f1] * invN - mu1 * mu1;
  float sc0 = rsqrtf(vv0 + EPS) * bng[f0], sh0 = bnb[f0] - mu0 * sc0;
  float sc1 = rsqrtf(vv1 + EPS) * bng[f1], sh1 = bnb[f1] - mu1 * sc1;
  float g0 = lng[f0], g1 = lng[f1], be0 = lnb[f0], be1 = lnb[f1];

  for (int node = wid; node < N; node += nwav) {
    const size_t b = (size_t)node * F;
    float x0 = x[b + f0], x1 = x[b + f1];
    float h0 = out[b + f0] * sc0 + sh0 + x0;
    float h1 = out[b + f1] * sc1 + sh1 + x1;
    float s = h0 + h1, q = h0 * h0 + h1 * h1;
    #pragma unroll
    for (int o = 32; o > 0; o >>= 1) {
      s += __shfl_xor(s, o, 64);
      q += __shfl_xor(q, o, 64);
    }
    float mu = s * (1.f / 128.f);
    float var = q * (1.f / 128.f) - mu * mu;
    float rs = rsqrtf(var + EPS);
    float y0 = fmaxf((h0 - mu) * rs * g0 + be0, 0.f) + x0;
    float y1 = fmaxf((h1 - mu) * rs * g1 + be1, 0.f) + x1;
    out[b + f0] = y0;
    out[b + f1] = y1;
  }
}

// ---------------------------------------------------------------------------
extern "C" void kernel_launch(void* const* d_in, const int* in_sizes, int n_in,
                              void* d_out, int out_size, void* d_ws, size_t ws_size,
                              hipStream_t stream)
{
  const float* x   = (const float*)d_in[0];
  const int*   ei  = (const int*)d_in[1];
  const float* ea  = (const float*)d_in[2];
  const float* Wf  = (const float*)d_in[3];
  const float* bf  = (const float*)d_in[4];
  const float* Ws  = (const float*)d_in[5];
  const float* bs  = (const float*)d_in[6];
  const float* bng = (const float*)d_in[7];
  const float* bnb = (const float*)d_in[8];
  const float* lng = (const float*)d_in[9];
  const float* lnb = (const float*)d_in[10];

  const int N = in_sizes[0] / F;
  const int E = in_sizes[1] / 2;
  const int* srcA = ei;
  const int* dstA = ei + E;
  float* out = (float*)d_out;

  const int chunks = (E + CHK - 1) / CHK;
  const int chunksEven = (chunks + 1) & ~1;
  const int Epad = chunksEven * CHK + 128;   // sd lookahead + stage pad

  char* w = (char*)d_ws;
  size_t off = 0;
  auto up = [](size_t v) { return (v + 255) & ~(size_t)255; };
  float*  tabdst = (float*)(w + off);  off = up(off + (size_t)N * 256 * sizeof(float));
  u32*    tabsrc = (u32*)(w + off);    off = up(off + (size_t)N * F * sizeof(u32));
  int2*   sd     = (int2*)(w + off);   off = up(off + (size_t)Epad * sizeof(int2));
  int*    cursor = (int*)(w + off);    off = up(off + (size_t)N * sizeof(int));
  int*    cnt    = (int*)(w + off);    size_t cntOff = off;
                                       off = up(off + (size_t)N * sizeof(int));
  float*  sums   = (float*)(w + off);  size_t sumsEnd = off + 256 * sizeof(float);
                                       off = up(sumsEnd);
  float*  eap    = (float*)(w + off);  off = up(off + (size_t)Epad * EDIM * sizeof(float));

  // cnt and sums are adjacent -> one memset covers both
  hipMemsetAsync(cnt, 0, sumsEnd - cntOff, stream);
  hipMemsetAsync(sd + E, 0, (size_t)(Epad - E) * sizeof(int2), stream);
  hipMemsetAsync(eap + (size_t)E * EDIM, 0,
                 (size_t)(Epad - E) * EDIM * sizeof(float), stream);
  hipMemsetAsync(out, 0, (size_t)N * F * sizeof(float), stream);

  count_deg<<<(E + 255) / 256, 256, 0, stream>>>(dstA, cnt, E);
  const int cpt = (N + 1023) / 1024;
  scan_k<<<1, 1024, 0, stream>>>(cnt, cursor, N, cpt);

  // fused: gemm (even blocks) || csr-fill (odd blocks)
  const int gB = ((N + 63) / 64) * 8;
  const int fB = (E + 255) / 256;
  const int fusedGrid = 2 * (gB > fB ? gB : fB);
  gemm_fill<<<fusedGrid, 256, 0, stream>>>(
      x, Wf, Ws, bf, bs, tabdst, (unsigned short*)tabsrc, N,
      dstA, srcA, ea, cursor, sd, eap, E, gB, fB);

  aggregate_lds<<<chunks, 128, 0, stream>>>(
      tabdst, tabsrc, (const float4*)eap, (const int4*)sd, Wf, Ws, out, E);

  bn_stats<<<256, 256, 0, stream>>>(out, sums, N);
  finalize<<<(N + 3) / 4, 256, 0, stream>>>(x, out, sums, bng, bnb, lng, lnb, N);
}